// Round 8
// baseline (103.188 us; speedup 1.0000x reference)
//
#include <hip/hip_runtime.h>
#include <math.h>

// Problem constants (fixed shapes from reference)
#define KNUM 256
#define HH 62
#define WW 64
#define NPLANES 768        // N*C = 4*192
#define NBLK 1536          // 2 blocks per plane (w-halves)
#define JV 1024            // vectors per plane
#define M_TOT (NPLANES*JV) // 786432
#define QL_SIZE (NPLANES*HH*WW) // 3047424

// d_out layout (concatenated tuple, float32):
#define OFF_MSE   QL_SIZE
#define OFF_INDS  (QL_SIZE + 1)
#define OFF_RATE  (OFF_INDS + M_TOT)

// d_ws layout: [0,1536) mse partials, [1536,3072) rate partials (floats);
// int kmin array at float-offset 4096, 512 per block.
#define WS_MSE  0
#define WS_RATE NBLK
#define WS_KOFF 4096

#define XT_STRIDE 65   // bank(w*65+h) = (w+h)%32 -> <=2-way everywhere (free)
#define TAB_STRIDE 12  // 48B pair-entry, 16B-aligned: {cx0,cx1,cy0,cy1,cz0,cz1,cw0,cw1,q0,q1,-,-}

typedef float v2f __attribute__((ext_vector_type(2)));

// v_pk_fma_f32 d = c*y + acc, src1 (y) broadcast from one 32-bit half via
// op_sel/op_sel_hi (correctness verified R5-R7, absmax 0.0).
__device__ __forceinline__ v2f pk_fma_ylo(v2f c, v2f y, v2f acc) {
    v2f d;
    asm("v_pk_fma_f32 %0, %1, %2, %3 op_sel:[0,0,0] op_sel_hi:[1,0,1]"
        : "=v"(d) : "v"(c), "v"(y), "v"(acc));
    return d;
}
__device__ __forceinline__ v2f pk_fma_ylo_acc(v2f c, v2f y, v2f d) {
    asm("v_pk_fma_f32 %0, %1, %2, %0 op_sel:[0,0,0] op_sel_hi:[1,0,1]"
        : "+v"(d) : "v"(c), "v"(y));
    return d;
}
__device__ __forceinline__ v2f pk_fma_yhi_acc(v2f c, v2f y, v2f d) {
    asm("v_pk_fma_f32 %0, %1, %2, %0 op_sel:[0,1,0] op_sel_hi:[1,1,1]"
        : "+v"(d) : "v"(c), "v"(y));
    return d;
}

// Phase 1: distance argmin only. 1536 blocks (half-plane) x 256 threads,
// each wave scans one 64-codeword quarter (32 pair-bodies), 8 vectors/lane.
// Merge is fully parallel (256 threads x 2 vectors), no serial epilogue.
__launch_bounds__(256, 5)
__global__ void vq_dist(const float* __restrict__ latents,
                        const float* __restrict__ codebook,
                        const float* __restrict__ log_pmf,
                        int* __restrict__ ws_k,
                        float* __restrict__ out) {
    __shared__ __align__(16) float xt[32 * XT_STRIDE];     // half-plane [w][h], 8.3 KB
    __shared__ __align__(16) float tab[129 * TAB_STRIDE];  // pair-interleaved codebook
    __shared__ float2 ex[4][512];                          // per-wave argmin posts, 16 KB

    const int t    = threadIdx.x;
    const int wave = t >> 6;
    const int lane = t & 63;
    const int blk  = blockIdx.x;
    const int pl   = blk >> 1;
    const int hf   = blk & 1;
    const float* plane = latents + (size_t)pl * (HH * WW);

    // ---- stage pair-interleaved codebook table (first 128 threads) ----
    if (t < 128) {
        float4 c0 = ((const float4*)codebook)[2 * t];
        float4 c1 = ((const float4*)codebook)[2 * t + 1];
        float l20 = log_pmf[2 * t]     * (-1.44269504088896340736f);
        float l21 = log_pmf[2 * t + 1] * (-1.44269504088896340736f);
        float q0 = c0.x * c0.x + c0.y * c0.y + c0.z * c0.z + c0.w * c0.w + l20 * 100.0f;
        float q1 = c1.x * c1.x + c1.y * c1.y + c1.z * c1.z + c1.w * c1.w + l21 * 100.0f;
        float* e = &tab[t * TAB_STRIDE];
        e[0] = c0.x; e[1] = c1.x; e[2] = c0.y; e[3] = c1.y;
        e[4] = c0.z; e[5] = c1.z; e[6] = c0.w; e[7] = c1.w;
        e[8] = q0;   e[9] = q1;
    }

    // ---- stage half-plane transposed (pad rows 62,63 = rows 60,61) ----
    for (int s = t; s < (HH * 8); s += 256) {   // 62 rows x 8 float4
        int h  = s >> 3;
        int wq = s & 7;
        float4 v = ((const float4*)plane)[h * 16 + hf * 8 + wq];
        int w0 = wq * 4;
        xt[(w0 + 0) * XT_STRIDE + h] = v.x;
        xt[(w0 + 1) * XT_STRIDE + h] = v.y;
        xt[(w0 + 2) * XT_STRIDE + h] = v.z;
        xt[(w0 + 3) * XT_STRIDE + h] = v.w;
        if (h >= 60) {
            int h2 = h + 2;
            xt[(w0 + 0) * XT_STRIDE + h2] = v.x;
            xt[(w0 + 1) * XT_STRIDE + h2] = v.y;
            xt[(w0 + 2) * XT_STRIDE + h2] = v.z;
            xt[(w0 + 3) * XT_STRIDE + h2] = v.w;
        }
    }
    __syncthreads();

    // ---- per-lane: 8 vectors j = lane + 64*i ----
    v2f y01[8], y23[8];
    float dmin[8];
    int   kmin[8];
#pragma unroll
    for (int i = 0; i < 8; ++i) {
        int j  = lane + 64 * i;
        int w  = j >> 4;
        int hc = j & 15;
        const float* p = &xt[w * XT_STRIDE + hc * 4];
        y01[i] = (v2f){-2.0f * p[0], -2.0f * p[1]};
        y23[i] = (v2f){-2.0f * p[2], -2.0f * p[3]};
        dmin[i] = INFINITY;
        kmin[i] = 0;
    }

    // ---- this wave's quarter: 32 pair-bodies, prefetch-by-1 ----
    const float* eb = &tab[wave * 32 * TAB_STRIDE];
    float4 f0 = *(const float4*)(eb + 0);
    float4 f1 = *(const float4*)(eb + 4);
    v2f    qq = *(const v2f*)(eb + 8);
#pragma unroll 2
    for (int k2 = 0; k2 < 32; ++k2) {
        const float* en = eb + (k2 + 1) * TAB_STRIDE;   // last iter: pad entry, unused
        float4 nf0 = *(const float4*)(en + 0);
        float4 nf1 = *(const float4*)(en + 4);
        v2f    nqq = *(const v2f*)(en + 8);

        v2f cx2 = (v2f){f0.x, f0.y};
        v2f cy2 = (v2f){f0.z, f0.w};
        v2f cz2 = (v2f){f1.x, f1.y};
        v2f cw2 = (v2f){f1.z, f1.w};
        int k = wave * 64 + k2 * 2;
#pragma unroll
        for (int i = 0; i < 8; ++i) {
            v2f d2 = pk_fma_ylo(cx2, y01[i], qq);
            d2 = pk_fma_yhi_acc(cy2, y01[i], d2);
            d2 = pk_fma_ylo_acc(cz2, y23[i], d2);
            d2 = pk_fma_yhi_acc(cw2, y23[i], d2);
            float nm = fminf(fminf(d2.x, d2.y), dmin[i]);   // v_min3_f32
            int kp = k + (int)(d2.y < d2.x);                // tie -> lower k
            kmin[i] = (dmin[i] == nm) ? kmin[i] : kp;       // old (lower k) wins ties
            dmin[i] = nm;
        }
        f0 = nf0; f1 = nf1; qq = nqq;
    }

    // ---- parallel ordered merge: every wave posts, 256 threads fold 2 vectors each ----
#pragma unroll
    for (int i = 0; i < 8; ++i)
        ex[wave][lane + 64 * i] = (float2){dmin[i], (float)kmin[i]};
    __syncthreads();

#pragma unroll
    for (int r = 0; r < 2; ++r) {
        int j = t + 256 * r;
        float2 m = ex[0][j];
#pragma unroll
        for (int w = 1; w < 4; ++w) {
            float2 e = ex[w][j];
            bool better = e.x < m.x;    // strict <: lower k-range wins ties
            m.x = better ? e.x : m.x;
            m.y = better ? e.y : m.y;
        }
        ws_k[(size_t)blk * 512 + j] = (int)m.y;
        out[OFF_INDS + (size_t)pl * JV + hf * 512 + j] = m.y;
    }
}

// Phase 2: gather q, mse/rate, transposed ql write.
__launch_bounds__(256, 8)
__global__ void vq_apply(const float* __restrict__ latents,
                         const float* __restrict__ codebook,
                         const float* __restrict__ log_pmf,
                         const int* __restrict__ ws_k,
                         float* __restrict__ ws_out,
                         float* __restrict__ out) {
    __shared__ __align__(16) float xt[32 * XT_STRIDE];
    __shared__ float4 cbv[KNUM];
    __shared__ float  l2v[KNUM];
    __shared__ float  wred[8];

    const int t   = threadIdx.x;
    const int blk = blockIdx.x;
    const int pl  = blk >> 1;
    const int hf  = blk & 1;
    const float* plane = latents + (size_t)pl * (HH * WW);

    cbv[t] = ((const float4*)codebook)[t];
    l2v[t] = log_pmf[t] * (-1.44269504088896340736f);

    for (int s = t; s < (HH * 8); s += 256) {
        int h  = s >> 3;
        int wq = s & 7;
        float4 v = ((const float4*)plane)[h * 16 + hf * 8 + wq];
        int w0 = wq * 4;
        xt[(w0 + 0) * XT_STRIDE + h] = v.x;
        xt[(w0 + 1) * XT_STRIDE + h] = v.y;
        xt[(w0 + 2) * XT_STRIDE + h] = v.z;
        xt[(w0 + 3) * XT_STRIDE + h] = v.w;
        if (h >= 60) {
            int h2 = h + 2;
            xt[(w0 + 0) * XT_STRIDE + h2] = v.x;
            xt[(w0 + 1) * XT_STRIDE + h2] = v.y;
            xt[(w0 + 2) * XT_STRIDE + h2] = v.z;
            xt[(w0 + 3) * XT_STRIDE + h2] = v.w;
        }
    }
    __syncthreads();

    float mse_acc = 0.0f;
    float rate_acc = 0.0f;
#pragma unroll
    for (int r = 0; r < 2; ++r) {
        int j  = t + 256 * r;
        int w  = j >> 4;
        int hc = j & 15;
        int k  = ws_k[(size_t)blk * 512 + j];
        float4 c = cbv[k];
        rate_acc += l2v[k];
        float* p = &xt[w * XT_STRIDE + hc * 4];
        float e0 = c.x - p[0];
        float e1 = c.y - p[1];
        float e2 = c.z - p[2];
        float e3 = c.w - p[3];
        mse_acc += e0 * e0 + e1 * e1 + e2 * e2 + e3 * e3;
        p[0] = c.x; p[1] = c.y; p[2] = c.z; p[3] = c.w;   // overwrite x with q
    }
    __syncthreads();

    // crop/transpose write-out: ql[pl, h, hf*32 + w] = xt[w][h], h < 62
    for (int s = t; s < HH * 32; s += 256) {
        int h = s >> 5;
        int w = s & 31;
        out[(size_t)pl * (HH * WW) + h * WW + hf * 32 + w] = xt[w * XT_STRIDE + h];
    }

    // block reduction -> per-block partials
#pragma unroll
    for (int off = 32; off > 0; off >>= 1) {
        mse_acc  += __shfl_down(mse_acc, off, 64);
        rate_acc += __shfl_down(rate_acc, off, 64);
    }
    int wave = t >> 6, lane = t & 63;
    if (lane == 0) { wred[wave] = mse_acc; wred[4 + wave] = rate_acc; }
    __syncthreads();
    if (t == 0) {
        ws_out[WS_MSE + blk]  = wred[0] + wred[1] + wred[2] + wred[3];
        ws_out[WS_RATE + blk] = wred[4] + wred[5] + wred[6] + wred[7];
    }
}

__global__ void vq_reduce(const float* __restrict__ ws, float* __restrict__ out) {
    __shared__ float wred[8];
    int t = threadIdx.x;   // 256 threads
    float m = 0.0f, r = 0.0f;
#pragma unroll
    for (int s = 0; s < 6; ++s) {
        m += ws[WS_MSE + t + 256 * s];
        r += ws[WS_RATE + t + 256 * s];
    }
#pragma unroll
    for (int off = 32; off > 0; off >>= 1) {
        m += __shfl_down(m, off, 64);
        r += __shfl_down(r, off, 64);
    }
    int wave = t >> 6, lane = t & 63;
    if (lane == 0) { wred[wave] = m; wred[4 + wave] = r; }
    __syncthreads();
    if (t == 0) {
        out[OFF_MSE]      = (wred[0] + wred[1] + wred[2] + wred[3]) * (1.0f / 3145728.0f);
        out[OFF_RATE]     = wred[4] + wred[5] + wred[6] + wred[7];
        out[OFF_RATE + 1] = 0.0f;
        out[OFF_RATE + 2] = 0.0f;
    }
}

extern "C" void kernel_launch(void* const* d_in, const int* in_sizes, int n_in,
                              void* d_out, int out_size, void* d_ws, size_t ws_size,
                              hipStream_t stream) {
    const float* latents  = (const float*)d_in[0];
    const float* codebook = (const float*)d_in[1];
    const float* log_pmf  = (const float*)d_in[2];
    float* out = (float*)d_out;
    float* ws  = (float*)d_ws;
    int*   wsk = (int*)ws + WS_KOFF;

    vq_dist<<<NBLK, 256, 0, stream>>>(latents, codebook, log_pmf, wsk, out);
    vq_apply<<<NBLK, 256, 0, stream>>>(latents, codebook, log_pmf, wsk, ws, out);
    vq_reduce<<<1, 256, 0, stream>>>(ws, out);
}

// Round 9
// 99.235 us; speedup vs baseline: 1.0398x; 1.0398x over previous
//
#include <hip/hip_runtime.h>
#include <math.h>

// Problem constants (fixed shapes from reference)
#define KNUM 256
#define HH 62
#define WW 64
#define NPLANES 768        // N*C = 4*192
#define NBLK 1536          // 2 blocks per plane (w-halves)
#define JV 1024            // vectors per plane
#define M_TOT (NPLANES*JV) // 786432
#define QL_SIZE (NPLANES*HH*WW) // 3047424

// d_out layout (concatenated tuple, float32):
#define OFF_MSE   QL_SIZE
#define OFF_INDS  (QL_SIZE + 1)
#define OFF_RATE  (OFF_INDS + M_TOT)

// d_ws layout (floats): per-block partials
#define WS_MSE  0
#define WS_RATE NBLK

#define XT_STRIDE 65   // bank(w*65+h) = (w+h)%32 -> <=2-way everywhere (free)
#define TAB_STRIDE 12  // 48B pair-entry, 16B-aligned: {cx0,cx1,cy0,cy1,cz0,cz1,cw0,cw1,q0,q1,l20,l21}

typedef float v2f __attribute__((ext_vector_type(2)));

// v_pk_fma_f32 d = c*y + acc, src1 (y) broadcast from one 32-bit half via
// op_sel/op_sel_hi (correctness verified R5-R8, absmax 0.0).
__device__ __forceinline__ v2f pk_fma_ylo(v2f c, v2f y, v2f acc) {
    v2f d;
    asm("v_pk_fma_f32 %0, %1, %2, %3 op_sel:[0,0,0] op_sel_hi:[1,0,1]"
        : "=v"(d) : "v"(c), "v"(y), "v"(acc));
    return d;
}
__device__ __forceinline__ v2f pk_fma_ylo_acc(v2f c, v2f y, v2f d) {
    asm("v_pk_fma_f32 %0, %1, %2, %0 op_sel:[0,0,0] op_sel_hi:[1,0,1]"
        : "+v"(d) : "v"(c), "v"(y));
    return d;
}
__device__ __forceinline__ v2f pk_fma_yhi_acc(v2f c, v2f y, v2f d) {
    asm("v_pk_fma_f32 %0, %1, %2, %0 op_sel:[0,1,0] op_sel_hi:[1,1,1]"
        : "+v"(d) : "v"(c), "v"(y));
    return d;
}

// Single kernel: 1536 blocks (half-plane) x 256 threads, 5 blocks/CU.
// Each wave scans one 64-codeword quarter (32 pair-bodies), 8 vectors/lane.
// Epilogue (merge + gather + mse + ql) is fully parallel across 256 threads
// (R7's wave0-serial tail + 3 barriers cost ~2-3 us; R8's split kernel cost
// ~4 us of duplicate staging + launch).
__launch_bounds__(256, 5)
__global__ void vq_main(const float* __restrict__ latents,
                        const float* __restrict__ codebook,
                        const float* __restrict__ log_pmf,
                        float* __restrict__ ws_out,
                        float* __restrict__ out) {
    __shared__ __align__(16) float xt[32 * XT_STRIDE];     // half-plane [w][h], 8.3 KB
    __shared__ __align__(16) float tab[129 * TAB_STRIDE];  // pair-interleaved codebook, 6.2 KB
    __shared__ float2 ex[4][512];                          // per-wave argmin posts, 16 KB
    __shared__ float  wred[8];

    const int t    = threadIdx.x;
    const int wave = t >> 6;
    const int lane = t & 63;
    const int blk  = blockIdx.x;
    const int pl   = blk >> 1;
    const int hf   = blk & 1;
    const float* plane = latents + (size_t)pl * (HH * WW);

    // ---- stage pair-interleaved codebook table (first 128 threads) ----
    if (t < 128) {
        float4 c0 = ((const float4*)codebook)[2 * t];
        float4 c1 = ((const float4*)codebook)[2 * t + 1];
        float l20 = log_pmf[2 * t]     * (-1.44269504088896340736f);
        float l21 = log_pmf[2 * t + 1] * (-1.44269504088896340736f);
        float q0 = c0.x * c0.x + c0.y * c0.y + c0.z * c0.z + c0.w * c0.w + l20 * 100.0f;
        float q1 = c1.x * c1.x + c1.y * c1.y + c1.z * c1.z + c1.w * c1.w + l21 * 100.0f;
        float* e = &tab[t * TAB_STRIDE];
        e[0] = c0.x; e[1] = c1.x; e[2] = c0.y; e[3] = c1.y;
        e[4] = c0.z; e[5] = c1.z; e[6] = c0.w; e[7] = c1.w;
        e[8] = q0;   e[9] = q1;   e[10] = l20; e[11] = l21;
    }

    // ---- stage half-plane transposed (pad rows 62,63 = rows 60,61) ----
    for (int s = t; s < (HH * 8); s += 256) {   // 62 rows x 8 float4
        int h  = s >> 3;
        int wq = s & 7;
        float4 v = ((const float4*)plane)[h * 16 + hf * 8 + wq];
        int w0 = wq * 4;
        xt[(w0 + 0) * XT_STRIDE + h] = v.x;
        xt[(w0 + 1) * XT_STRIDE + h] = v.y;
        xt[(w0 + 2) * XT_STRIDE + h] = v.z;
        xt[(w0 + 3) * XT_STRIDE + h] = v.w;
        if (h >= 60) {
            int h2 = h + 2;
            xt[(w0 + 0) * XT_STRIDE + h2] = v.x;
            xt[(w0 + 1) * XT_STRIDE + h2] = v.y;
            xt[(w0 + 2) * XT_STRIDE + h2] = v.z;
            xt[(w0 + 3) * XT_STRIDE + h2] = v.w;
        }
    }
    __syncthreads();

    // ---- per-lane: 8 vectors j = lane + 64*i ----
    v2f y01[8], y23[8];
    float dmin[8];
    int   kmin[8];
#pragma unroll
    for (int i = 0; i < 8; ++i) {
        int j  = lane + 64 * i;
        int w  = j >> 4;
        int hc = j & 15;
        const float* p = &xt[w * XT_STRIDE + hc * 4];
        y01[i] = (v2f){-2.0f * p[0], -2.0f * p[1]};
        y23[i] = (v2f){-2.0f * p[2], -2.0f * p[3]};
        dmin[i] = INFINITY;
        kmin[i] = 0;
    }

    // ---- this wave's quarter: 32 pair-bodies, prefetch-by-1 ----
    const float* eb = &tab[wave * 32 * TAB_STRIDE];
    float4 f0 = *(const float4*)(eb + 0);
    float4 f1 = *(const float4*)(eb + 4);
    v2f    qq = *(const v2f*)(eb + 8);
#pragma unroll 2
    for (int k2 = 0; k2 < 32; ++k2) {
        const float* en = eb + (k2 + 1) * TAB_STRIDE;   // last iter: pad entry, unused
        float4 nf0 = *(const float4*)(en + 0);
        float4 nf1 = *(const float4*)(en + 4);
        v2f    nqq = *(const v2f*)(en + 8);

        v2f cx2 = (v2f){f0.x, f0.y};
        v2f cy2 = (v2f){f0.z, f0.w};
        v2f cz2 = (v2f){f1.x, f1.y};
        v2f cw2 = (v2f){f1.z, f1.w};
        int k = wave * 64 + k2 * 2;
#pragma unroll
        for (int i = 0; i < 8; ++i) {
            v2f d2 = pk_fma_ylo(cx2, y01[i], qq);
            d2 = pk_fma_yhi_acc(cy2, y01[i], d2);
            d2 = pk_fma_ylo_acc(cz2, y23[i], d2);
            d2 = pk_fma_yhi_acc(cw2, y23[i], d2);
            float nm = fminf(fminf(d2.x, d2.y), dmin[i]);   // v_min3_f32
            int kp = k + (int)(d2.y < d2.x);                // tie -> lower k
            kmin[i] = (dmin[i] == nm) ? kmin[i] : kp;       // old (lower k) wins ties
            dmin[i] = nm;
        }
        f0 = nf0; f1 = nf1; qq = nqq;
    }

    // ---- every wave posts its partial argmins ----
#pragma unroll
    for (int i = 0; i < 8; ++i)
        ex[wave][lane + 64 * i] = (float2){dmin[i], (float)kmin[i]};
    __syncthreads();

    // ---- parallel merge + epilogue: 256 threads x 2 vectors ----
    float mse_acc = 0.0f;
    float rate_acc = 0.0f;
#pragma unroll
    for (int r = 0; r < 2; ++r) {
        int j = t + 256 * r;
        float2 m = ex[0][j];
#pragma unroll
        for (int w2 = 1; w2 < 4; ++w2) {
            float2 e = ex[w2][j];
            bool better = e.x < m.x;    // strict <: lower k-range wins ties
            m.x = better ? e.x : m.x;
            m.y = better ? e.y : m.y;
        }
        int k = (int)m.y;
        const float* e = &tab[(k >> 1) * TAB_STRIDE + (k & 1)];
        float cx = e[0], cy = e[2], cz = e[4], cw = e[6], l2 = e[10];
        rate_acc += l2;
        int w  = j >> 4;
        int hc = j & 15;
        float* p = &xt[w * XT_STRIDE + hc * 4];
        float e0 = cx - p[0];
        float e1 = cy - p[1];
        float e2 = cz - p[2];
        float e3 = cw - p[3];
        mse_acc += e0 * e0 + e1 * e1 + e2 * e2 + e3 * e3;
        p[0] = cx; p[1] = cy; p[2] = cz; p[3] = cw;   // overwrite x with q
        out[OFF_INDS + (size_t)pl * JV + hf * 512 + j] = m.y;
    }
    __syncthreads();

    // ---- crop/transpose write-out: ql[pl, h, hf*32 + w] = xt[w][h], h < 62 ----
    for (int s = t; s < HH * 32; s += 256) {
        int h = s >> 5;
        int w = s & 31;
        out[(size_t)pl * (HH * WW) + h * WW + hf * 32 + w] = xt[w * XT_STRIDE + h];
    }

    // ---- block reduction of mse/rate -> per-block partial ----
#pragma unroll
    for (int off = 32; off > 0; off >>= 1) {
        mse_acc  += __shfl_down(mse_acc, off, 64);
        rate_acc += __shfl_down(rate_acc, off, 64);
    }
    if (lane == 0) { wred[wave] = mse_acc; wred[4 + wave] = rate_acc; }
    __syncthreads();
    if (t == 0) {
        ws_out[WS_MSE + blk]  = wred[0] + wred[1] + wred[2] + wred[3];
        ws_out[WS_RATE + blk] = wred[4] + wred[5] + wred[6] + wred[7];
    }
}

__global__ void vq_reduce(const float* __restrict__ ws, float* __restrict__ out) {
    __shared__ float wred[8];
    int t = threadIdx.x;   // 256 threads
    float m = 0.0f, r = 0.0f;
#pragma unroll
    for (int s = 0; s < 6; ++s) {
        m += ws[WS_MSE + t + 256 * s];
        r += ws[WS_RATE + t + 256 * s];
    }
#pragma unroll
    for (int off = 32; off > 0; off >>= 1) {
        m += __shfl_down(m, off, 64);
        r += __shfl_down(r, off, 64);
    }
    int wave = t >> 6, lane = t & 63;
    if (lane == 0) { wred[wave] = m; wred[4 + wave] = r; }
    __syncthreads();
    if (t == 0) {
        out[OFF_MSE]      = (wred[0] + wred[1] + wred[2] + wred[3]) * (1.0f / 3145728.0f);
        out[OFF_RATE]     = wred[4] + wred[5] + wred[6] + wred[7];
        out[OFF_RATE + 1] = 0.0f;
        out[OFF_RATE + 2] = 0.0f;
    }
}

extern "C" void kernel_launch(void* const* d_in, const int* in_sizes, int n_in,
                              void* d_out, int out_size, void* d_ws, size_t ws_size,
                              hipStream_t stream) {
    const float* latents  = (const float*)d_in[0];
    const float* codebook = (const float*)d_in[1];
    const float* log_pmf  = (const float*)d_in[2];
    float* out = (float*)d_out;
    float* ws  = (float*)d_ws;

    vq_main<<<NBLK, 256, 0, stream>>>(latents, codebook, log_pmf, ws, out);
    vq_reduce<<<1, 256, 0, stream>>>(ws, out);
}